// Round 1
// baseline (1347.382 us; speedup 1.0000x reference)
//
#include <hip/hip_runtime.h>
#include <hip/hip_bf16.h>
#include <math.h>

#define P_TOT   100000
#define NBLK    3125          // P_TOT / BM
#define BM      32

// ws float offsets
#define OFF_WT    0           // 65536: combined [k][perm(n)] weight transpose
#define OFF_BSUM  65536       // 256
#define OFF_W1AT  65792       // 8192: att_W1 path-half transposed [k][perm2(n)]
#define OFF_CTXP  73984       // 128
#define OFF_MISC  74112       // [0]=safety, [1]=invZ
#define OFF_E     74128       // 100000: exp(score) per path
#define OFF_PE    174128      // 3125 partial sums of e
#define OFF_PAGG  177256      // 3125*64 partial sums of e*h

__device__ __forceinline__ float sigm(float x){ return 1.f/(1.f+expf(-x)); }

// ---------------------------------------------------------------- prep
__global__ __launch_bounds__(256) void kprep(
    const int* __restrict__ user_idx, const int* __restrict__ item_idx,
    const float* __restrict__ user_emb, const float* __restrict__ item_emb,
    const float* __restrict__ W_ih, const float* __restrict__ W_hh,
    const float* __restrict__ b_ih, const float* __restrict__ b_hh,
    const float* __restrict__ att_W1, const float* __restrict__ att_b1,
    const float* __restrict__ saf_W1, const float* __restrict__ saf_b1,
    const float* __restrict__ saf_W2, const float* __restrict__ saf_b2,
    float* __restrict__ ws)
{
  int t = threadIdx.x;
  __shared__ float ctx[128];
  {
    int n = t;
    // perm(n): n = tx*8 + half*4 + j  ->  pos = half*128 + tx*4 + j
    int pos = ((n>>2)&1)*128 + (n>>3)*4 + (n&3);
    for (int k=0;k<192;++k) ws[OFF_WT + k*256 + pos] = W_ih[n*192+k];
    for (int k=0;k<64;++k)  ws[OFF_WT + (192+k)*256 + pos] = W_hh[n*64+k];
    ws[OFF_BSUM + pos] = b_ih[n] + b_hh[n];
  }
  if (t < 128) {
    int n = t;
    int pos2 = ((n>>2)&1)*64 + (n>>3)*4 + (n&3);
    for (int k=0;k<64;++k) ws[OFF_W1AT + k*128 + pos2] = att_W1[n*192+k];
  }
  if (t < 64) {
    ctx[t]    = user_emb[user_idx[0]*64 + t];
    ctx[64+t] = item_emb[item_idx[0]*64 + t];
  }
  __syncthreads();
  if (t < 128) {
    float s = att_b1[t];
    for (int k=0;k<128;++k) s = fmaf(att_W1[t*192 + 64 + k], ctx[k], s);
    ws[OFF_CTXP + t] = s;
  }
  if (t < 32) {
    float s = saf_b1[t];
    for (int k=0;k<128;++k) s = fmaf(saf_W1[t*128+k], ctx[k], s);
    s = fmaxf(s, 0.f);
    float v = s * saf_W2[t];
    v += __shfl_xor(v,1); v += __shfl_xor(v,2); v += __shfl_xor(v,4);
    v += __shfl_xor(v,8); v += __shfl_xor(v,16);
    if (t==0) ws[OFF_MISC+0] = 1.f/(1.f+expf(-(v + saf_b2[0])));
  }
}

// ---------------------------------------------------------------- main LSTM + attention
__global__ __launch_bounds__(256) void klstm(
    const int* __restrict__ node_ids, const int* __restrict__ node_types,
    const int* __restrict__ rel_idx,
    const float* __restrict__ user_emb, const float* __restrict__ item_emb,
    const float* __restrict__ relation_emb, const float* __restrict__ node_type_emb,
    const float* __restrict__ att_W2, const float* __restrict__ att_b2,
    float* __restrict__ ws)
{
  __shared__ float Xs[BM][256];   // feats+h (K=256); reused as Z; reused for hidden
  __shared__ float Us[8192];      // W chunk / att W1 / es + reduction
  const float* WT   = ws + OFF_WT;
  const float* bsum = ws + OFF_BSUM;
  const float* W1aT = ws + OFF_W1AT;
  const float* ctxp = ws + OFF_CTXP;
  float* ws_e  = ws + OFF_E;
  float* p_e   = ws + OFF_PE;
  float* p_agg = ws + OFF_PAGG;

  const int t   = threadIdx.x;
  const int bid = blockIdx.x;
  const int p0  = bid * BM;
  const int tx = t & 31, ty = t >> 5;          // GEMM tile: cols tx*8.., paths ty*4..
  const int up_p = t >> 3, up_d0 = (t & 7) << 3; // update/gather mapping

  float bias[8];
  {
    float4 b0 = *(const float4*)(bsum + tx*4);
    float4 b1 = *(const float4*)(bsum + 128 + tx*4);
    bias[0]=b0.x; bias[1]=b0.y; bias[2]=b0.z; bias[3]=b0.w;
    bias[4]=b1.x; bias[5]=b1.y; bias[6]=b1.z; bias[7]=b1.w;
  }
  float c[8];
  #pragma unroll
  for (int j=0;j<8;++j){ c[j]=0.f; Xs[up_p][192+up_d0+j]=0.f; }

  for (int step=0; step<4; ++step) {
    __syncthreads();                       // h-writes / prior-step Z-reads done
    {
      int pg = p0 + up_p;
      int l8 = t & 7;
      int nid = node_ids [pg*4 + step];
      int nt  = node_types[pg*4 + step];
      int rid = rel_idx  [pg*4 + step];
      const float* nsrc = (nt==0 ? user_emb : item_emb) + nid*64 + l8*8;
      const float* tsrc = node_type_emb + nt*64 + l8*8;
      const float* rsrc = relation_emb + rid*64 + l8*8;
      *(float4*)&Xs[up_p][      l8*8  ] = ((const float4*)nsrc)[0];
      *(float4*)&Xs[up_p][      l8*8+4] = ((const float4*)nsrc)[1];
      *(float4*)&Xs[up_p][ 64 + l8*8  ] = ((const float4*)tsrc)[0];
      *(float4*)&Xs[up_p][ 64 + l8*8+4] = ((const float4*)tsrc)[1];
      *(float4*)&Xs[up_p][128 + l8*8  ] = ((const float4*)rsrc)[0];
      *(float4*)&Xs[up_p][128 + l8*8+4] = ((const float4*)rsrc)[1];
    }
    float acc[4][8];
    #pragma unroll
    for (int pi=0;pi<4;++pi)
      #pragma unroll
      for (int j=0;j<8;++j) acc[pi][j] = bias[j];

    for (int kc=0;kc<8;++kc) {
      __syncthreads();                     // gather done (kc=0) / prev chunk reads done
      {
        const float4* src = (const float4*)(WT + kc*8192 + t*32);
        float4* dst = (float4*)(Us + t*32);
        #pragma unroll
        for (int i=0;i<8;++i) dst[i] = src[i];
      }
      __syncthreads();
      #pragma unroll
      for (int k=0;k<32;++k) {
        float4 w0 = *(const float4*)(Us + k*256 + tx*4);
        float4 w1 = *(const float4*)(Us + k*256 + 128 + tx*4);
        #pragma unroll
        for (int pi=0;pi<4;++pi) {
          float xv = Xs[ty*4+pi][kc*32+k];
          acc[pi][0] = fmaf(xv, w0.x, acc[pi][0]);
          acc[pi][1] = fmaf(xv, w0.y, acc[pi][1]);
          acc[pi][2] = fmaf(xv, w0.z, acc[pi][2]);
          acc[pi][3] = fmaf(xv, w0.w, acc[pi][3]);
          acc[pi][4] = fmaf(xv, w1.x, acc[pi][4]);
          acc[pi][5] = fmaf(xv, w1.y, acc[pi][5]);
          acc[pi][6] = fmaf(xv, w1.z, acc[pi][6]);
          acc[pi][7] = fmaf(xv, w1.w, acc[pi][7]);
        }
      }
    }
    __syncthreads();                       // all GEMM reads of Xs done -> Xs dead
    #pragma unroll
    for (int pi=0;pi<4;++pi) {
      int p = ty*4+pi;
      *(float4*)&Xs[p][tx*8  ] = make_float4(acc[pi][0],acc[pi][1],acc[pi][2],acc[pi][3]);
      *(float4*)&Xs[p][tx*8+4] = make_float4(acc[pi][4],acc[pi][5],acc[pi][6],acc[pi][7]);
    }
    __syncthreads();                       // Z visible
    {
      float4 a0 = *(const float4*)&Xs[up_p][      up_d0  ];
      float4 a1 = *(const float4*)&Xs[up_p][      up_d0+4];
      float4 f0 = *(const float4*)&Xs[up_p][ 64 + up_d0  ];
      float4 f1 = *(const float4*)&Xs[up_p][ 64 + up_d0+4];
      float4 g0 = *(const float4*)&Xs[up_p][128 + up_d0  ];
      float4 g1 = *(const float4*)&Xs[up_p][128 + up_d0+4];
      float4 o0 = *(const float4*)&Xs[up_p][192 + up_d0  ];
      float4 o1 = *(const float4*)&Xs[up_p][192 + up_d0+4];
      float zi[8]={a0.x,a0.y,a0.z,a0.w,a1.x,a1.y,a1.z,a1.w};
      float zf[8]={f0.x,f0.y,f0.z,f0.w,f1.x,f1.y,f1.z,f1.w};
      float zg[8]={g0.x,g0.y,g0.z,g0.w,g1.x,g1.y,g1.z,g1.w};
      float zo[8]={o0.x,o0.y,o0.z,o0.w,o1.x,o1.y,o1.z,o1.w};
      float hh[8];
      #pragma unroll
      for (int j=0;j<8;++j) {
        float ig = sigm(zi[j]);
        float fg = sigm(zf[j]);
        float gg = tanhf(zg[j]);
        float og = sigm(zo[j]);
        c[j] = fmaf(fg, c[j], ig*gg);
        hh[j] = og * tanhf(c[j]);
      }
      *(float4*)&Xs[up_p][192+up_d0  ] = make_float4(hh[0],hh[1],hh[2],hh[3]);
      *(float4*)&Xs[up_p][192+up_d0+4] = make_float4(hh[4],hh[5],hh[6],hh[7]);
    }
  }
  __syncthreads();
  // ---- attention hidden: relu(h @ W1a^T + ctxpart) -> Xs cols 0..127
  {
    const float4* src = (const float4*)(W1aT + t*32);
    float4* dst = (float4*)(Us + t*32);
    #pragma unroll
    for (int i=0;i<8;++i) dst[i] = src[i];
  }
  __syncthreads();
  if (tx < 16) {
    float hid[4][8];
    #pragma unroll
    for (int pi=0;pi<4;++pi)
      #pragma unroll
      for (int j=0;j<8;++j) hid[pi][j]=0.f;
    for (int k=0;k<64;++k) {
      float4 w0 = *(const float4*)(Us + k*128 + tx*4);
      float4 w1 = *(const float4*)(Us + k*128 + 64 + tx*4);
      #pragma unroll
      for (int pi=0;pi<4;++pi) {
        float xv = Xs[ty*4+pi][192+k];
        hid[pi][0] = fmaf(xv, w0.x, hid[pi][0]);
        hid[pi][1] = fmaf(xv, w0.y, hid[pi][1]);
        hid[pi][2] = fmaf(xv, w0.z, hid[pi][2]);
        hid[pi][3] = fmaf(xv, w0.w, hid[pi][3]);
        hid[pi][4] = fmaf(xv, w1.x, hid[pi][4]);
        hid[pi][5] = fmaf(xv, w1.y, hid[pi][5]);
        hid[pi][6] = fmaf(xv, w1.z, hid[pi][6]);
        hid[pi][7] = fmaf(xv, w1.w, hid[pi][7]);
      }
    }
    float4 cp0 = *(const float4*)(ctxp + tx*8);
    float4 cp1 = *(const float4*)(ctxp + tx*8 + 4);
    #pragma unroll
    for (int pi=0;pi<4;++pi) {
      int p = ty*4+pi;
      *(float4*)&Xs[p][tx*8  ] = make_float4(fmaxf(hid[pi][0]+cp0.x,0.f),
                                             fmaxf(hid[pi][1]+cp0.y,0.f),
                                             fmaxf(hid[pi][2]+cp0.z,0.f),
                                             fmaxf(hid[pi][3]+cp0.w,0.f));
      *(float4*)&Xs[p][tx*8+4] = make_float4(fmaxf(hid[pi][4]+cp1.x,0.f),
                                             fmaxf(hid[pi][5]+cp1.y,0.f),
                                             fmaxf(hid[pi][6]+cp1.z,0.f),
                                             fmaxf(hid[pi][7]+cp1.w,0.f));
    }
  }
  __syncthreads();
  // ---- score = hidden @ att_W2^T + b2 ; e = exp(score)
  float sc = 0.f;
  {
    const float* w2 = att_W2 + (t&7)*16;
    const float* hp = &Xs[t>>3][(t&7)*16];
    #pragma unroll
    for (int i=0;i<16;i+=4) {
      float4 a = *(const float4*)(hp+i);
      float4 b = *(const float4*)(w2+i);
      sc = fmaf(a.x,b.x,sc); sc = fmaf(a.y,b.y,sc);
      sc = fmaf(a.z,b.z,sc); sc = fmaf(a.w,b.w,sc);
    }
  }
  sc += __shfl_xor(sc,1); sc += __shfl_xor(sc,2); sc += __shfl_xor(sc,4);
  if ((t&7)==0) {
    float e = expf(sc + att_b2[0]);
    Us[t>>3] = e;                 // es[32]
    ws_e[p0 + (t>>3)] = e;
  }
  __syncthreads();
  // ---- per-block partial sums: Σe and Σ e*h[d]
  {
    int d = t & 63, pg = t >> 6;
    float a = 0.f;
    #pragma unroll
    for (int pi=0;pi<8;++pi)
      a = fmaf(Us[pg*8+pi], Xs[pg*8+pi][192+d], a);
    Us[64 + pg*64 + d] = a;
  }
  __syncthreads();
  if (t < 64)
    p_agg[bid*64 + t] = Us[64+t] + Us[128+t] + Us[192+t] + Us[256+t];
  if (t < 32) {
    float e2 = Us[t];
    e2 += __shfl_xor(e2,1); e2 += __shfl_xor(e2,2); e2 += __shfl_xor(e2,4);
    e2 += __shfl_xor(e2,8); e2 += __shfl_xor(e2,16);
    if (t==0) p_e[bid] = e2;
  }
}

// ---------------------------------------------------------------- reduce + heads
__global__ __launch_bounds__(256) void kreduce(
    const float* __restrict__ val_W1, const float* __restrict__ val_b1,
    const float* __restrict__ val_W2, const float* __restrict__ val_b2,
    float* __restrict__ ws, float* __restrict__ d_out)
{
  const float* p_e   = ws + OFF_PE;
  const float* p_agg = ws + OFF_PAGG;
  __shared__ float aggL[64];
  __shared__ float red[256];
  int t = threadIdx.x;
  float pe = 0.f;
  for (int i=t;i<NBLK;i+=256) pe += p_e[i];
  red[t] = pe; __syncthreads();
  for (int s=128;s>0;s>>=1){ if(t<s) red[t]+=red[t+s]; __syncthreads(); }
  float Z = red[0];
  if (t<64){
    float a = 0.f;
    for (int b=0;b<NBLK;++b) a += p_agg[b*64+t];
    aggL[t] = a / Z;
  }
  if (t==0) ws[OFF_MISC+1] = 1.f/Z;
  __syncthreads();
  if (t<32){
    float hv = val_b1[t];
    for (int k=0;k<64;++k) hv = fmaf(aggL[k], val_W1[t*64+k], hv);
    hv = fmaxf(hv, 0.f);
    float v = hv * val_W2[t];
    v += __shfl_xor(v,1); v += __shfl_xor(v,2); v += __shfl_xor(v,4);
    v += __shfl_xor(v,8); v += __shfl_xor(v,16);
    // q_value = value + (advantage - mean(advantage)) == value exactly (adv is [1])
    if (t==0) d_out[0] = (v + val_b2[0]) * ws[OFF_MISC+0];
  }
}

// ---------------------------------------------------------------- att weights out
__global__ __launch_bounds__(256) void kweights(
    const float* __restrict__ ws, float* __restrict__ d_out)
{
  int p = blockIdx.x*256 + threadIdx.x;
  if (p < P_TOT) d_out[1+p] = ws[OFF_E + p] * ws[OFF_MISC+1];
}

// ---------------------------------------------------------------- launch
extern "C" void kernel_launch(void* const* d_in, const int* in_sizes, int n_in,
                              void* d_out, int out_size, void* d_ws, size_t ws_size,
                              hipStream_t stream) {
  const int*   user_idx   = (const int*)  d_in[0];
  const int*   item_idx   = (const int*)  d_in[1];
  const int*   node_ids   = (const int*)  d_in[2];
  const int*   node_types = (const int*)  d_in[3];
  const int*   rel_idx    = (const int*)  d_in[4];
  const float* user_emb   = (const float*)d_in[5];
  const float* item_emb   = (const float*)d_in[6];
  const float* rel_emb    = (const float*)d_in[7];
  const float* ntype_emb  = (const float*)d_in[8];
  const float* W_ih       = (const float*)d_in[9];
  const float* W_hh       = (const float*)d_in[10];
  const float* b_ih       = (const float*)d_in[11];
  const float* b_hh       = (const float*)d_in[12];
  const float* att_W1     = (const float*)d_in[13];
  const float* att_b1     = (const float*)d_in[14];
  const float* att_W2     = (const float*)d_in[15];
  const float* att_b2     = (const float*)d_in[16];
  const float* val_W1     = (const float*)d_in[17];
  const float* val_b1     = (const float*)d_in[18];
  const float* val_W2     = (const float*)d_in[19];
  const float* val_b2     = (const float*)d_in[20];
  const float* saf_W1     = (const float*)d_in[25];
  const float* saf_b1     = (const float*)d_in[26];
  const float* saf_W2     = (const float*)d_in[27];
  const float* saf_b2     = (const float*)d_in[28];
  float* ws  = (float*)d_ws;
  float* out = (float*)d_out;

  hipLaunchKernelGGL(kprep, dim3(1), dim3(256), 0, stream,
                     user_idx, item_idx, user_emb, item_emb,
                     W_ih, W_hh, b_ih, b_hh, att_W1, att_b1,
                     saf_W1, saf_b1, saf_W2, saf_b2, ws);
  hipLaunchKernelGGL(klstm, dim3(NBLK), dim3(256), 0, stream,
                     node_ids, node_types, rel_idx,
                     user_emb, item_emb, rel_emb, ntype_emb,
                     att_W2, att_b2, ws);
  hipLaunchKernelGGL(kreduce, dim3(1), dim3(256), 0, stream,
                     val_W1, val_b1, val_W2, val_b2, ws, out);
  hipLaunchKernelGGL(kweights, dim3((P_TOT+255)/256), dim3(256), 0, stream,
                     ws, out);
}

// Round 2
// 604.994 us; speedup vs baseline: 2.2271x; 2.2271x over previous
//
#include <hip/hip_runtime.h>
#include <math.h>

#define P_TOT 100000
#define BM    16
#define NBLK  6250

// ws float offsets
#define OFF_BIH  0        // 49152 f32-slots: 192 frag-blocks (6kc x 2hl x 16nt) x 1KB bf16
#define OFF_BHH  49152    // 16384: 64 frag-blocks (2kc x 2hl x 16nt)
#define OFF_BA   65536    // 8192:  32 frag-blocks (2kc x 2hl x 8nt)
#define OFF_BSUM 73728    // 256  (b_ih+b_hh, natural order)
#define OFF_CTXP 73984    // 128  (ctx part of att hidden preact)
#define OFF_MISC 74112    // [0]=safety, [1]=invZ
#define OFF_E    74128    // 100000 exp(score)
#define OFF_PE   174128   // 6250 partial sum e
#define OFF_PAGG 180384   // 6250*64 partial sum e*h

typedef short bf16x8 __attribute__((ext_vector_type(8)));
typedef float f32x4  __attribute__((ext_vector_type(4)));

#define MFMA16(a,b,c) __builtin_amdgcn_mfma_f32_16x16x32_bf16((a),(b),(c),0,0,0)

__device__ __forceinline__ void cvthl(float v, unsigned short& h, unsigned short& l){
  unsigned int u  = __float_as_uint(v);
  unsigned int hr = (u + 0x7fffu + ((u>>16)&1u)) >> 16;
  float hf = __uint_as_float(hr<<16);
  unsigned int u2 = __float_as_uint(v - hf);
  unsigned int lr = (u2 + 0x7fffu + ((u2>>16)&1u)) >> 16;
  h = (unsigned short)hr; l = (unsigned short)lr;
}
__device__ __forceinline__ float sigm_f(float x){ return 1.f/(1.f+__expf(-x)); }
__device__ __forceinline__ float tanh_f(float x){
  float e2 = __expf(2.f*x);
  return (e2-1.f)/(e2+1.f);
}

// ---------------------------------------------------------------- prep
__global__ __launch_bounds__(256) void kprep(
    const int* __restrict__ user_idx, const int* __restrict__ item_idx,
    const float* __restrict__ user_emb, const float* __restrict__ item_emb,
    const float* __restrict__ W_ih, const float* __restrict__ W_hh,
    const float* __restrict__ b_ih, const float* __restrict__ b_hh,
    const float* __restrict__ att_W1, const float* __restrict__ att_b1,
    const float* __restrict__ saf_W1, const float* __restrict__ saf_b1,
    const float* __restrict__ saf_W2, const float* __restrict__ saf_b2,
    float* __restrict__ ws)
{
  const int t = threadIdx.x;
  // fragment-major bf16 hi/lo packing: frag elem e: lane l=e>>3, j=e&7
  for (int fb = blockIdx.x; fb < 288; fb += gridDim.x){
    const float* src; int base, rowlen, kc, hl, ntg;
    if (fb < 192){ kc = fb>>5; int rem = fb&31; hl = rem>>4; ntg = rem&15;
                   base = OFF_BIH + fb*256; src = W_ih; rowlen = 192; }
    else if (fb < 256){ int f2 = fb-192; kc = f2>>5; int rem = f2&31; hl = rem>>4; ntg = rem&15;
                   base = OFF_BHH + f2*256; src = W_hh; rowlen = 64; }
    else { int f3 = fb-256; kc = f3>>4; int rem = f3&15; hl = rem>>3; ntg = rem&7;
                   base = OFF_BA + f3*256; src = att_W1; rowlen = 192; }
    unsigned short* dst = (unsigned short*)(ws + base);
    for (int e = t; e < 512; e += 256){
      int l = e>>3, j = e&7;
      int n = ntg*16 + (l&15);
      int k = kc*32 + (l>>4)*8 + j;
      float v = src[n*rowlen + k];
      unsigned short h, lo; cvthl(v, h, lo);
      dst[e] = hl ? lo : h;
    }
  }
  if (blockIdx.x == 0){
    __shared__ float ctx[128];
    if (t < 256) ws[OFF_BSUM+t] = b_ih[t] + b_hh[t];
    if (t < 64){
      ctx[t]    = user_emb[user_idx[0]*64 + t];
      ctx[64+t] = item_emb[item_idx[0]*64 + t];
    }
    __syncthreads();
    if (t < 128){
      float s = att_b1[t];
      for (int k=0;k<128;++k) s = fmaf(att_W1[t*192 + 64 + k], ctx[k], s);
      ws[OFF_CTXP + t] = s;
    }
    if (t < 32){
      float s = saf_b1[t];
      for (int k=0;k<128;++k) s = fmaf(saf_W1[t*128+k], ctx[k], s);
      s = fmaxf(s, 0.f);
      float v = s * saf_W2[t];
      v += __shfl_xor(v,1); v += __shfl_xor(v,2); v += __shfl_xor(v,4);
      v += __shfl_xor(v,8); v += __shfl_xor(v,16);
      if (t==0) ws[OFF_MISC+0] = 1.f/(1.f+expf(-(v + saf_b2[0])));
    }
  }
}

// ---------------------------------------------------------------- main: LSTM + attention (MFMA split-bf16)
// LDS map: phase1: Afeat [4s][2hl][16p] x 384B = 49152
// phase2 overlay: ZBUF @0 (16x256 f32 = 16384) | HBUF @16384 (16x64 f32 = 4096)
//                 AH @20480 ([2hl][16p]x128B = 4096) | HIDB @24576 (16x128 f32 = 8192)
//                 ES @32768 (64B) | PART @32896 (8x64 f32 = 2048)
__global__ __launch_bounds__(512,4) void klstm(
    const int* __restrict__ node_ids, const int* __restrict__ node_types,
    const int* __restrict__ rel_idx,
    const float* __restrict__ user_emb, const float* __restrict__ item_emb,
    const float* __restrict__ relation_emb, const float* __restrict__ node_type_emb,
    const float* __restrict__ att_W2, const float* __restrict__ att_b2,
    float* __restrict__ ws)
{
  __shared__ __align__(16) unsigned char smem[49152];
  const int t   = threadIdx.x;
  const int l   = t & 63, wid = t >> 6;
  const int ln  = l & 15, lk = l >> 4;
  const int bid = blockIdx.x, p0 = bid*BM;
  const int n0  = wid*32;
  const bf16x8* Bih = (const bf16x8*)(ws + OFF_BIH);
  const bf16x8* Bhh = (const bf16x8*)(ws + OFF_BHH);
  const bf16x8* Bab = (const bf16x8*)(ws + OFF_BA);
  const int swA = (ln&7)<<4;

  // ---- gather feats (4 steps) -> swizzled bf16 hi/lo A tiles
  if (t < 384){
    int r = t>>1, half = t&1;
    int s = r/48, rem = r - s*48, src = rem>>4, p = rem&15;
    int gi = (p0+p)*4 + s;
    const float* sp;
    if (src==0){ int nid = node_ids[gi]; sp = (node_types[gi]==0 ? user_emb : item_emb) + nid*64; }
    else if (src==1){ sp = node_type_emb + node_types[gi]*64; }
    else { sp = relation_emb + rel_idx[gi]*64; }
    const int sw = (p&7)<<4;
    const int rowH = ((s*2+0)*16 + p)*384;
    const int rowL = ((s*2+1)*16 + p)*384;
    #pragma unroll
    for (int ii=0; ii<4; ++ii){
      int i = half*4 + ii;
      float4 v0 = ((const float4*)sp)[i*2];
      float4 v1 = ((const float4*)sp)[i*2+1];
      float vv[8] = {v0.x,v0.y,v0.z,v0.w,v1.x,v1.y,v1.z,v1.w};
      unsigned short h[8], lo[8];
      #pragma unroll
      for (int j=0;j<8;++j) cvthl(vv[j], h[j], lo[j]);
      uint4 hq, lq;
      hq.x = (unsigned)h[0] | ((unsigned)h[1]<<16);  hq.y = (unsigned)h[2] | ((unsigned)h[3]<<16);
      hq.z = (unsigned)h[4] | ((unsigned)h[5]<<16);  hq.w = (unsigned)h[6] | ((unsigned)h[7]<<16);
      lq.x = (unsigned)lo[0]| ((unsigned)lo[1]<<16); lq.y = (unsigned)lo[2]| ((unsigned)lo[3]<<16);
      lq.z = (unsigned)lo[4]| ((unsigned)lo[5]<<16); lq.w = (unsigned)lo[6]| ((unsigned)lo[7]<<16);
      int kb = (src*64 + i*8)*2;
      *(uint4*)(smem + rowH + (kb ^ sw)) = hq;
      *(uint4*)(smem + rowL + (kb ^ sw)) = lq;
    }
  }
  // ---- acc init with bias (Z = X@Wc^T + (b_ih+b_hh))
  f32x4 acc[4][2];
  #pragma unroll
  for (int s=0;s<4;++s)
    #pragma unroll
    for (int nt=0;nt<2;++nt){
      float bv = ws[OFF_BSUM + n0 + nt*16 + ln];
      acc[s][nt] = (f32x4){bv,bv,bv,bv};
    }
  __syncthreads();

  // ---- phase 1: Zfeat for all 4 steps (K=192), B frags reused across steps
  #pragma unroll 2
  for (int kc=0;kc<6;++kc){
    bf16x8 bh0 = Bih[(unsigned)(((kc*2+0)*16 + wid*2+0)*64 + l)];
    bf16x8 bh1 = Bih[(unsigned)(((kc*2+0)*16 + wid*2+1)*64 + l)];
    bf16x8 bl0 = Bih[(unsigned)(((kc*2+1)*16 + wid*2+0)*64 + l)];
    bf16x8 bl1 = Bih[(unsigned)(((kc*2+1)*16 + wid*2+1)*64 + l)];
    #pragma unroll
    for (int s=0;s<4;++s){
      bf16x8 ah = *(const bf16x8*)(smem + ((s*2+0)*16+ln)*384 + ((kc*64 + lk*16) ^ swA));
      bf16x8 al = *(const bf16x8*)(smem + ((s*2+1)*16+ln)*384 + ((kc*64 + lk*16) ^ swA));
      acc[s][0] = MFMA16(ah, bh0, acc[s][0]);
      acc[s][0] = MFMA16(al, bh0, acc[s][0]);
      acc[s][0] = MFMA16(ah, bl0, acc[s][0]);
      acc[s][1] = MFMA16(ah, bh1, acc[s][1]);
      acc[s][1] = MFMA16(al, bh1, acc[s][1]);
      acc[s][1] = MFMA16(ah, bl1, acc[s][1]);
    }
  }
  __syncthreads();   // Afeat dead; overlay region live from here

  // ---- phase 2: recurrence
  const int gp = t>>5, gd = (t&31)*2;     // gate thread -> (path, 2 dims)
  const int swg = (gp&7)<<4;
  float c0 = 0.f, c1 = 0.f;
  #pragma unroll
  for (int s=0;s<4;++s){
    if (s > 0){
      #pragma unroll
      for (int kc=0;kc<2;++kc){
        bf16x8 ah = *(const bf16x8*)(smem + 20480 +        ln*128 + ((kc*64 + lk*16) ^ swA));
        bf16x8 al = *(const bf16x8*)(smem + 20480 + 2048 + ln*128 + ((kc*64 + lk*16) ^ swA));
        bf16x8 bh0 = Bhh[(unsigned)(((kc*2+0)*16 + wid*2+0)*64 + l)];
        bf16x8 bh1 = Bhh[(unsigned)(((kc*2+0)*16 + wid*2+1)*64 + l)];
        bf16x8 bl0 = Bhh[(unsigned)(((kc*2+1)*16 + wid*2+0)*64 + l)];
        bf16x8 bl1 = Bhh[(unsigned)(((kc*2+1)*16 + wid*2+1)*64 + l)];
        acc[s][0] = MFMA16(ah, bh0, acc[s][0]);
        acc[s][0] = MFMA16(al, bh0, acc[s][0]);
        acc[s][0] = MFMA16(ah, bl0, acc[s][0]);
        acc[s][1] = MFMA16(ah, bh1, acc[s][1]);
        acc[s][1] = MFMA16(al, bh1, acc[s][1]);
        acc[s][1] = MFMA16(ah, bl1, acc[s][1]);
      }
    }
    // write Z tile to LDS (C layout: row=(l>>4)*4+r, col=l&15)
    #pragma unroll
    for (int nt=0;nt<2;++nt)
      #pragma unroll
      for (int r=0;r<4;++r)
        *(float*)(smem + (lk*4+r)*1024 + (n0 + nt*16 + ln)*4) = acc[s][nt][r];
    __syncthreads();
    // gates (f32): z = [i | f | g | o]
    {
      float2 zi = *(float2*)(smem + gp*1024 +        gd*4);
      float2 zf = *(float2*)(smem + gp*1024 + 256  + gd*4);
      float2 zg = *(float2*)(smem + gp*1024 + 512  + gd*4);
      float2 zo = *(float2*)(smem + gp*1024 + 768  + gd*4);
      float i0 = sigm_f(zi.x), i1 = sigm_f(zi.y);
      float f0 = sigm_f(zf.x), f1 = sigm_f(zf.y);
      float g0 = tanh_f(zg.x), g1 = tanh_f(zg.y);
      float o0 = sigm_f(zo.x), o1 = sigm_f(zo.y);
      c0 = fmaf(f0, c0, i0*g0);
      c1 = fmaf(f1, c1, i1*g1);
      float h0 = o0 * tanh_f(c0);
      float h1 = o1 * tanh_f(c1);
      if (s == 3) *(float2*)(smem + 16384 + gp*256 + gd*4) = make_float2(h0, h1);
      unsigned short hh0,ll0,hh1,ll1;
      cvthl(h0, hh0, ll0); cvthl(h1, hh1, ll1);
      *(unsigned*)(smem + 20480 +        gp*128 + ((gd*2) ^ swg)) = (unsigned)hh0 | ((unsigned)hh1<<16);
      *(unsigned*)(smem + 20480 + 2048 + gp*128 + ((gd*2) ^ swg)) = (unsigned)ll0 | ((unsigned)ll1<<16);
    }
    __syncthreads();
  }

  // ---- attention hidden: relu(h @ BA + ctxp)   (N=128 -> waves 0..3)
  if (wid < 4){
    f32x4 acc2[2];
    #pragma unroll
    for (int nt=0;nt<2;++nt){
      float cv = ws[OFF_CTXP + wid*32 + nt*16 + ln];
      acc2[nt] = (f32x4){cv,cv,cv,cv};
    }
    #pragma unroll
    for (int kc=0;kc<2;++kc){
      bf16x8 ah = *(const bf16x8*)(smem + 20480 +        ln*128 + ((kc*64 + lk*16) ^ swA));
      bf16x8 al = *(const bf16x8*)(smem + 20480 + 2048 + ln*128 + ((kc*64 + lk*16) ^ swA));
      bf16x8 bh0 = Bab[(unsigned)(((kc*2+0)*8 + wid*2+0)*64 + l)];
      bf16x8 bh1 = Bab[(unsigned)(((kc*2+0)*8 + wid*2+1)*64 + l)];
      bf16x8 bl0 = Bab[(unsigned)(((kc*2+1)*8 + wid*2+0)*64 + l)];
      bf16x8 bl1 = Bab[(unsigned)(((kc*2+1)*8 + wid*2+1)*64 + l)];
      acc2[0] = MFMA16(ah, bh0, acc2[0]);
      acc2[0] = MFMA16(al, bh0, acc2[0]);
      acc2[0] = MFMA16(ah, bl0, acc2[0]);
      acc2[1] = MFMA16(ah, bh1, acc2[1]);
      acc2[1] = MFMA16(al, bh1, acc2[1]);
      acc2[1] = MFMA16(ah, bl1, acc2[1]);
    }
    #pragma unroll
    for (int nt=0;nt<2;++nt)
      #pragma unroll
      for (int r=0;r<4;++r)
        *(float*)(smem + 24576 + (lk*4+r)*512 + (wid*32 + nt*16 + ln)*4) = fmaxf(acc2[nt][r], 0.f);
  }
  __syncthreads();
  // ---- score = hidden . att_W2 + b2 ; e = exp(score)
  {
    int sp2 = t>>5, seg = t&31;
    float4 a = *(const float4*)(smem + 24576 + sp2*512 + seg*16);
    float4 w = *(const float4*)(att_W2 + seg*4);
    float sc = a.x*w.x; sc = fmaf(a.y,w.y,sc); sc = fmaf(a.z,w.z,sc); sc = fmaf(a.w,w.w,sc);
    sc += __shfl_xor(sc,1); sc += __shfl_xor(sc,2); sc += __shfl_xor(sc,4);
    sc += __shfl_xor(sc,8); sc += __shfl_xor(sc,16);
    if (seg == 0){
      float e = __expf(sc + att_b2[0]);
      *(float*)(smem + 32768 + sp2*4) = e;
      ws[OFF_E + p0 + sp2] = e;
    }
  }
  __syncthreads();
  // ---- partial sums: sum(e), sum(e*h)
  {
    int pg = t>>6, d = t&63;
    const float* es = (const float*)(smem + 32768);
    float a = es[pg*2]   * (*(const float*)(smem + 16384 + (pg*2  )*256 + d*4))
            + es[pg*2+1] * (*(const float*)(smem + 16384 + (pg*2+1)*256 + d*4));
    *(float*)(smem + 32896 + (pg*64+d)*4) = a;
  }
  __syncthreads();
  if (t < 64){
    const float* part = (const float*)(smem + 32896);
    float a = 0.f;
    #pragma unroll
    for (int pg=0;pg<8;++pg) a += part[pg*64 + t];
    ws[OFF_PAGG + bid*64 + t] = a;
  }
  if (t < 16){
    float e2 = *(const float*)(smem + 32768 + t*4);
    e2 += __shfl_xor(e2,1); e2 += __shfl_xor(e2,2);
    e2 += __shfl_xor(e2,4); e2 += __shfl_xor(e2,8);
    if (t==0) ws[OFF_PE + bid] = e2;
  }
}

// ---------------------------------------------------------------- reduce + heads
__global__ __launch_bounds__(256) void kreduce(
    const float* __restrict__ val_W1, const float* __restrict__ val_b1,
    const float* __restrict__ val_W2, const float* __restrict__ val_b2,
    float* __restrict__ ws, float* __restrict__ d_out)
{
  const float* p_e   = ws + OFF_PE;
  const float* p_agg = ws + OFF_PAGG;
  __shared__ float aggL[64];
  __shared__ float red[256];
  int t = threadIdx.x;
  float pe = 0.f;
  for (int i=t;i<NBLK;i+=256) pe += p_e[i];
  red[t] = pe; __syncthreads();
  for (int s=128;s>0;s>>=1){ if(t<s) red[t]+=red[t+s]; __syncthreads(); }
  float Z = red[0];
  __syncthreads();
  {
    int q = t>>6, d = t&63;
    float a = 0.f;
    for (int b=q;b<NBLK;b+=4) a += p_agg[b*64 + d];
    red[t] = a;
  }
  __syncthreads();
  if (t < 64) aggL[t] = (red[t] + red[64+t] + red[128+t] + red[192+t]) / Z;
  if (t == 0) ws[OFF_MISC+1] = 1.f/Z;
  __syncthreads();
  if (t < 32){
    float hv = val_b1[t];
    for (int k=0;k<64;++k) hv = fmaf(aggL[k], val_W1[t*64+k], hv);
    hv = fmaxf(hv, 0.f);
    float v = hv * val_W2[t];
    v += __shfl_xor(v,1); v += __shfl_xor(v,2); v += __shfl_xor(v,4);
    v += __shfl_xor(v,8); v += __shfl_xor(v,16);
    // q_value = value + (advantage - mean(advantage)) == value (advantage is [1])
    if (t==0) d_out[0] = (v + val_b2[0]) * ws[OFF_MISC+0];
  }
}

// ---------------------------------------------------------------- att weights out
__global__ __launch_bounds__(256) void kweights(
    const float* __restrict__ ws, float* __restrict__ d_out)
{
  int p = blockIdx.x*256 + threadIdx.x;
  if (p < P_TOT) d_out[1+p] = ws[OFF_E + p] * ws[OFF_MISC+1];
}

// ---------------------------------------------------------------- launch
extern "C" void kernel_launch(void* const* d_in, const int* in_sizes, int n_in,
                              void* d_out, int out_size, void* d_ws, size_t ws_size,
                              hipStream_t stream) {
  const int*   user_idx   = (const int*)  d_in[0];
  const int*   item_idx   = (const int*)  d_in[1];
  const int*   node_ids   = (const int*)  d_in[2];
  const int*   node_types = (const int*)  d_in[3];
  const int*   rel_idx    = (const int*)  d_in[4];
  const float* user_emb   = (const float*)d_in[5];
  const float* item_emb   = (const float*)d_in[6];
  const float* rel_emb    = (const float*)d_in[7];
  const float* ntype_emb  = (const float*)d_in[8];
  const float* W_ih       = (const float*)d_in[9];
  const float* W_hh       = (const float*)d_in[10];
  const float* b_ih       = (const float*)d_in[11];
  const float* b_hh       = (const float*)d_in[12];
  const float* att_W1     = (const float*)d_in[13];
  const float* att_b1     = (const float*)d_in[14];
  const float* att_W2     = (const float*)d_in[15];
  const float* att_b2     = (const float*)d_in[16];
  const float* val_W1     = (const float*)d_in[17];
  const float* val_b1     = (const float*)d_in[18];
  const float* val_W2     = (const float*)d_in[19];
  const float* val_b2     = (const float*)d_in[20];
  const float* saf_W1     = (const float*)d_in[25];
  const float* saf_b1     = (const float*)d_in[26];
  const float* saf_W2     = (const float*)d_in[27];
  const float* saf_b2     = (const float*)d_in[28];
  float* ws  = (float*)d_ws;
  float* out = (float*)d_out;

  hipLaunchKernelGGL(kprep, dim3(64), dim3(256), 0, stream,
                     user_idx, item_idx, user_emb, item_emb,
                     W_ih, W_hh, b_ih, b_hh, att_W1, att_b1,
                     saf_W1, saf_b1, saf_W2, saf_b2, ws);
  hipLaunchKernelGGL(klstm, dim3(NBLK), dim3(512), 0, stream,
                     node_ids, node_types, rel_idx,
                     user_emb, item_emb, rel_emb, ntype_emb,
                     att_W2, att_b2, ws);
  hipLaunchKernelGGL(kreduce, dim3(1), dim3(256), 0, stream,
                     val_W1, val_b1, val_W2, val_b2, ws, out);
  hipLaunchKernelGGL(kweights, dim3((P_TOT+255)/256), dim3(256), 0, stream,
                     ws, out);
}

// Round 3
// 236.804 us; speedup vs baseline: 5.6899x; 2.5548x over previous
//
#include <hip/hip_runtime.h>
#include <math.h>

#define P_TOT 100000
#define BM    16
#define NBLK  6250

// ws float offsets
#define OFF_BIH   0        // 49152 f32-slots: 192 frag-blocks (6kc x 2hl x 16nt) x 1KB bf16
#define OFF_BHH   49152    // 16384: 64 frag-blocks (2kc x 2hl x 16nt)
#define OFF_BA    65536    // 8192:  32 frag-blocks (2kc x 2hl x 8nt)
#define OFF_BSUM  73728    // 256  (b_ih+b_hh, natural order)
#define OFF_CTXP  73984    // 128  (ctx part of att hidden preact)
#define OFF_MISC  74112    // [0]=safety, [1]=invZ
#define OFF_E     74128    // 100000 exp(score)
#define OFF_PE    174128   // 6250 partial sum e
#define OFF_PAGG  180384   // 6250*64 partial sum e*h
#define OFF_P2E   580384   // 64 stage-2 partial sum e
#define OFF_P2AGG 580448   // 256*64 stage-2 partial sum e*h

typedef short bf16x8 __attribute__((ext_vector_type(8)));
typedef float f32x4  __attribute__((ext_vector_type(4)));

#define MFMA16(a,b,c) __builtin_amdgcn_mfma_f32_16x16x32_bf16((a),(b),(c),0,0,0)

__device__ __forceinline__ void cvthl(float v, unsigned short& h, unsigned short& l){
  unsigned int u  = __float_as_uint(v);
  unsigned int hr = (u + 0x7fffu + ((u>>16)&1u)) >> 16;
  float hf = __uint_as_float(hr<<16);
  unsigned int u2 = __float_as_uint(v - hf);
  unsigned int lr = (u2 + 0x7fffu + ((u2>>16)&1u)) >> 16;
  h = (unsigned short)hr; l = (unsigned short)lr;
}
__device__ __forceinline__ float sigm_f(float x){ return 1.f/(1.f+__expf(-x)); }
__device__ __forceinline__ float tanh_f(float x){
  float e2 = __expf(2.f*x);
  return (e2-1.f)/(e2+1.f);
}

// ---------------------------------------------------------------- prep
__global__ __launch_bounds__(256) void kprep(
    const int* __restrict__ user_idx, const int* __restrict__ item_idx,
    const float* __restrict__ user_emb, const float* __restrict__ item_emb,
    const float* __restrict__ W_ih, const float* __restrict__ W_hh,
    const float* __restrict__ b_ih, const float* __restrict__ b_hh,
    const float* __restrict__ att_W1, const float* __restrict__ att_b1,
    const float* __restrict__ saf_W1, const float* __restrict__ saf_b1,
    const float* __restrict__ saf_W2, const float* __restrict__ saf_b2,
    float* __restrict__ ws)
{
  const int t = threadIdx.x;
  // fragment-major bf16 hi/lo packing: frag elem e: lane l=e>>3, j=e&7
  for (int fb = blockIdx.x; fb < 288; fb += gridDim.x){
    const float* src; int base, rowlen, kc, hl, ntg;
    if (fb < 192){ kc = fb>>5; int rem = fb&31; hl = rem>>4; ntg = rem&15;
                   base = OFF_BIH + fb*256; src = W_ih; rowlen = 192; }
    else if (fb < 256){ int f2 = fb-192; kc = f2>>5; int rem = f2&31; hl = rem>>4; ntg = rem&15;
                   base = OFF_BHH + f2*256; src = W_hh; rowlen = 64; }
    else { int f3 = fb-256; kc = f3>>4; int rem = f3&15; hl = rem>>3; ntg = rem&7;
                   base = OFF_BA + f3*256; src = att_W1; rowlen = 192; }
    unsigned short* dst = (unsigned short*)(ws + base);
    for (int e = t; e < 512; e += 256){
      int l = e>>3, j = e&7;
      int n = ntg*16 + (l&15);
      int k = kc*32 + (l>>4)*8 + j;
      float v = src[n*rowlen + k];
      unsigned short h, lo; cvthl(v, h, lo);
      dst[e] = hl ? lo : h;
    }
  }
  if (blockIdx.x == 0){
    __shared__ float ctx[128];
    if (t < 256) ws[OFF_BSUM+t] = b_ih[t] + b_hh[t];
    if (t < 64){
      ctx[t]    = user_emb[user_idx[0]*64 + t];
      ctx[64+t] = item_emb[item_idx[0]*64 + t];
    }
    __syncthreads();
    if (t < 128){
      float s = att_b1[t];
      for (int k=0;k<128;++k) s = fmaf(att_W1[t*192 + 64 + k], ctx[k], s);
      ws[OFF_CTXP + t] = s;
    }
    if (t < 32){
      float s = saf_b1[t];
      for (int k=0;k<128;++k) s = fmaf(saf_W1[t*128+k], ctx[k], s);
      s = fmaxf(s, 0.f);
      float v = s * saf_W2[t];
      v += __shfl_xor(v,1); v += __shfl_xor(v,2); v += __shfl_xor(v,4);
      v += __shfl_xor(v,8); v += __shfl_xor(v,16);
      if (t==0) ws[OFF_MISC+0] = 1.f/(1.f+expf(-(v + saf_b2[0])));
    }
  }
}

// ---------------------------------------------------------------- main: LSTM + attention (MFMA split-bf16)
__global__ __launch_bounds__(512,4) void klstm(
    const int* __restrict__ node_ids, const int* __restrict__ node_types,
    const int* __restrict__ rel_idx,
    const float* __restrict__ user_emb, const float* __restrict__ item_emb,
    const float* __restrict__ relation_emb, const float* __restrict__ node_type_emb,
    const float* __restrict__ att_W2, const float* __restrict__ att_b2,
    float* __restrict__ ws)
{
  __shared__ __align__(16) unsigned char smem[49152];
  const int t   = threadIdx.x;
  const int l   = t & 63, wid = t >> 6;
  const int ln  = l & 15, lk = l >> 4;
  const int bid = blockIdx.x, p0 = bid*BM;
  const int n0  = wid*32;
  const bf16x8* Bih = (const bf16x8*)(ws + OFF_BIH);
  const bf16x8* Bhh = (const bf16x8*)(ws + OFF_BHH);
  const bf16x8* Bab = (const bf16x8*)(ws + OFF_BA);
  const int swA = (ln&7)<<4;

  // ---- gather feats (4 steps) -> swizzled bf16 hi/lo A tiles
  if (t < 384){
    int r = t>>1, half = t&1;
    int s = r/48, rem = r - s*48, src = rem>>4, p = rem&15;
    int gi = (p0+p)*4 + s;
    const float* sp;
    if (src==0){ int nid = node_ids[gi]; sp = (node_types[gi]==0 ? user_emb : item_emb) + nid*64; }
    else if (src==1){ sp = node_type_emb + node_types[gi]*64; }
    else { sp = relation_emb + rel_idx[gi]*64; }
    const int sw = (p&7)<<4;
    const int rowH = ((s*2+0)*16 + p)*384;
    const int rowL = ((s*2+1)*16 + p)*384;
    #pragma unroll
    for (int ii=0; ii<4; ++ii){
      int i = half*4 + ii;
      float4 v0 = ((const float4*)sp)[i*2];
      float4 v1 = ((const float4*)sp)[i*2+1];
      float vv[8] = {v0.x,v0.y,v0.z,v0.w,v1.x,v1.y,v1.z,v1.w};
      unsigned short h[8], lo[8];
      #pragma unroll
      for (int j=0;j<8;++j) cvthl(vv[j], h[j], lo[j]);
      uint4 hq, lq;
      hq.x = (unsigned)h[0] | ((unsigned)h[1]<<16);  hq.y = (unsigned)h[2] | ((unsigned)h[3]<<16);
      hq.z = (unsigned)h[4] | ((unsigned)h[5]<<16);  hq.w = (unsigned)h[6] | ((unsigned)h[7]<<16);
      lq.x = (unsigned)lo[0]| ((unsigned)lo[1]<<16); lq.y = (unsigned)lo[2]| ((unsigned)lo[3]<<16);
      lq.z = (unsigned)lo[4]| ((unsigned)lo[5]<<16); lq.w = (unsigned)lo[6]| ((unsigned)lo[7]<<16);
      int kb = (src*64 + i*8)*2;
      *(uint4*)(smem + rowH + (kb ^ sw)) = hq;
      *(uint4*)(smem + rowL + (kb ^ sw)) = lq;
    }
  }
  // ---- acc init with bias (Z = X@Wc^T + (b_ih+b_hh))
  f32x4 acc[4][2];
  #pragma unroll
  for (int s=0;s<4;++s)
    #pragma unroll
    for (int nt=0;nt<2;++nt){
      float bv = ws[OFF_BSUM + n0 + nt*16 + ln];
      acc[s][nt] = (f32x4){bv,bv,bv,bv};
    }
  __syncthreads();

  // ---- phase 1: Zfeat for all 4 steps (K=192), B frags reused across steps
  #pragma unroll 2
  for (int kc=0;kc<6;++kc){
    bf16x8 bh0 = Bih[(unsigned)(((kc*2+0)*16 + wid*2+0)*64 + l)];
    bf16x8 bh1 = Bih[(unsigned)(((kc*2+0)*16 + wid*2+1)*64 + l)];
    bf16x8 bl0 = Bih[(unsigned)(((kc*2+1)*16 + wid*2+0)*64 + l)];
    bf16x8 bl1 = Bih[(unsigned)(((kc*2+1)*16 + wid*2+1)*64 + l)];
    #pragma unroll
    for (int s=0;s<4;++s){
      bf16x8 ah = *(const bf16x8*)(smem + ((s*2+0)*16+ln)*384 + ((kc*64 + lk*16) ^ swA));
      bf16x8 al = *(const bf16x8*)(smem + ((s*2+1)*16+ln)*384 + ((kc*64 + lk*16) ^ swA));
      acc[s][0] = MFMA16(ah, bh0, acc[s][0]);
      acc[s][0] = MFMA16(al, bh0, acc[s][0]);
      acc[s][0] = MFMA16(ah, bl0, acc[s][0]);
      acc[s][1] = MFMA16(ah, bh1, acc[s][1]);
      acc[s][1] = MFMA16(al, bh1, acc[s][1]);
      acc[s][1] = MFMA16(ah, bl1, acc[s][1]);
    }
  }
  __syncthreads();   // Afeat dead; overlay region live from here

  // ---- phase 2: recurrence
  const int gp = t>>5, gd = (t&31)*2;     // gate thread -> (path, 2 dims)
  const int swg = (gp&7)<<4;
  float c0 = 0.f, c1 = 0.f;
  #pragma unroll
  for (int s=0;s<4;++s){
    if (s > 0){
      #pragma unroll
      for (int kc=0;kc<2;++kc){
        bf16x8 ah = *(const bf16x8*)(smem + 20480 +        ln*128 + ((kc*64 + lk*16) ^ swA));
        bf16x8 al = *(const bf16x8*)(smem + 20480 + 2048 + ln*128 + ((kc*64 + lk*16) ^ swA));
        bf16x8 bh0 = Bhh[(unsigned)(((kc*2+0)*16 + wid*2+0)*64 + l)];
        bf16x8 bh1 = Bhh[(unsigned)(((kc*2+0)*16 + wid*2+1)*64 + l)];
        bf16x8 bl0 = Bhh[(unsigned)(((kc*2+1)*16 + wid*2+0)*64 + l)];
        bf16x8 bl1 = Bhh[(unsigned)(((kc*2+1)*16 + wid*2+1)*64 + l)];
        acc[s][0] = MFMA16(ah, bh0, acc[s][0]);
        acc[s][0] = MFMA16(al, bh0, acc[s][0]);
        acc[s][0] = MFMA16(ah, bl0, acc[s][0]);
        acc[s][1] = MFMA16(ah, bh1, acc[s][1]);
        acc[s][1] = MFMA16(al, bh1, acc[s][1]);
        acc[s][1] = MFMA16(ah, bl1, acc[s][1]);
      }
    }
    // write Z tile to LDS (C layout: row=(l>>4)*4+r, col=l&15)
    #pragma unroll
    for (int nt=0;nt<2;++nt)
      #pragma unroll
      for (int r=0;r<4;++r)
        *(float*)(smem + (lk*4+r)*1024 + (n0 + nt*16 + ln)*4) = acc[s][nt][r];
    __syncthreads();
    // gates (f32): z = [i | f | g | o]
    {
      float2 zi = *(float2*)(smem + gp*1024 +        gd*4);
      float2 zf = *(float2*)(smem + gp*1024 + 256  + gd*4);
      float2 zg = *(float2*)(smem + gp*1024 + 512  + gd*4);
      float2 zo = *(float2*)(smem + gp*1024 + 768  + gd*4);
      float i0 = sigm_f(zi.x), i1 = sigm_f(zi.y);
      float f0 = sigm_f(zf.x), f1 = sigm_f(zf.y);
      float g0 = tanh_f(zg.x), g1 = tanh_f(zg.y);
      float o0 = sigm_f(zo.x), o1 = sigm_f(zo.y);
      c0 = fmaf(f0, c0, i0*g0);
      c1 = fmaf(f1, c1, i1*g1);
      float h0 = o0 * tanh_f(c0);
      float h1 = o1 * tanh_f(c1);
      if (s == 3) *(float2*)(smem + 16384 + gp*256 + gd*4) = make_float2(h0, h1);
      unsigned short hh0,ll0,hh1,ll1;
      cvthl(h0, hh0, ll0); cvthl(h1, hh1, ll1);
      *(unsigned*)(smem + 20480 +        gp*128 + ((gd*2) ^ swg)) = (unsigned)hh0 | ((unsigned)hh1<<16);
      *(unsigned*)(smem + 20480 + 2048 + gp*128 + ((gd*2) ^ swg)) = (unsigned)ll0 | ((unsigned)ll1<<16);
    }
    __syncthreads();
  }

  // ---- attention hidden: relu(h @ BA + ctxp)   (N=128 -> waves 0..3)
  if (wid < 4){
    f32x4 acc2[2];
    #pragma unroll
    for (int nt=0;nt<2;++nt){
      float cv = ws[OFF_CTXP + wid*32 + nt*16 + ln];
      acc2[nt] = (f32x4){cv,cv,cv,cv};
    }
    #pragma unroll
    for (int kc=0;kc<2;++kc){
      bf16x8 ah = *(const bf16x8*)(smem + 20480 +        ln*128 + ((kc*64 + lk*16) ^ swA));
      bf16x8 al = *(const bf16x8*)(smem + 20480 + 2048 + ln*128 + ((kc*64 + lk*16) ^ swA));
      bf16x8 bh0 = Bab[(unsigned)(((kc*2+0)*8 + wid*2+0)*64 + l)];
      bf16x8 bh1 = Bab[(unsigned)(((kc*2+0)*8 + wid*2+1)*64 + l)];
      bf16x8 bl0 = Bab[(unsigned)(((kc*2+1)*8 + wid*2+0)*64 + l)];
      bf16x8 bl1 = Bab[(unsigned)(((kc*2+1)*8 + wid*2+1)*64 + l)];
      acc2[0] = MFMA16(ah, bh0, acc2[0]);
      acc2[0] = MFMA16(al, bh0, acc2[0]);
      acc2[0] = MFMA16(ah, bl0, acc2[0]);
      acc2[1] = MFMA16(ah, bh1, acc2[1]);
      acc2[1] = MFMA16(al, bh1, acc2[1]);
      acc2[1] = MFMA16(ah, bl1, acc2[1]);
    }
    #pragma unroll
    for (int nt=0;nt<2;++nt)
      #pragma unroll
      for (int r=0;r<4;++r)
        *(float*)(smem + 24576 + (lk*4+r)*512 + (wid*32 + nt*16 + ln)*4) = fmaxf(acc2[nt][r], 0.f);
  }
  __syncthreads();
  // ---- score = hidden . att_W2 + b2 ; e = exp(score)
  {
    int sp2 = t>>5, seg = t&31;
    float4 a = *(const float4*)(smem + 24576 + sp2*512 + seg*16);
    float4 w = *(const float4*)(att_W2 + seg*4);
    float sc = a.x*w.x; sc = fmaf(a.y,w.y,sc); sc = fmaf(a.z,w.z,sc); sc = fmaf(a.w,w.w,sc);
    sc += __shfl_xor(sc,1); sc += __shfl_xor(sc,2); sc += __shfl_xor(sc,4);
    sc += __shfl_xor(sc,8); sc += __shfl_xor(sc,16);
    if (seg == 0){
      float e = __expf(sc + att_b2[0]);
      *(float*)(smem + 32768 + sp2*4) = e;
      ws[OFF_E + p0 + sp2] = e;
    }
  }
  __syncthreads();
  // ---- partial sums: sum(e), sum(e*h)
  {
    int pg = t>>6, d = t&63;
    const float* es = (const float*)(smem + 32768);
    float a = es[pg*2]   * (*(const float*)(smem + 16384 + (pg*2  )*256 + d*4))
            + es[pg*2+1] * (*(const float*)(smem + 16384 + (pg*2+1)*256 + d*4));
    *(float*)(smem + 32896 + (pg*64+d)*4) = a;
  }
  __syncthreads();
  if (t < 64){
    const float* part = (const float*)(smem + 32896);
    float a = 0.f;
    #pragma unroll
    for (int pg=0;pg<8;++pg) a += part[pg*64 + t];
    ws[OFF_PAGG + bid*64 + t] = a;
  }
  if (t < 16){
    float e2 = *(const float*)(smem + 32768 + t*4);
    e2 += __shfl_xor(e2,1); e2 += __shfl_xor(e2,2);
    e2 += __shfl_xor(e2,4); e2 += __shfl_xor(e2,8);
    if (t==0) ws[OFF_PE + bid] = e2;
  }
}

// ---------------------------------------------------------------- reduce stage A: 64 blocks
__global__ __launch_bounds__(256) void kredA(float* __restrict__ ws)
{
  const float* p_e   = ws + OFF_PE;
  const float* p_agg = ws + OFF_PAGG;
  __shared__ float red[256];
  const int b = blockIdx.x, t = threadIdx.x;
  const int s = b*4 + (t>>6), d = t&63;
  float a = 0.f;
  for (int row = s; row < NBLK; row += 256) a += p_agg[row*64 + d];
  ws[OFF_P2AGG + s*64 + d] = a;
  // p_e partial over contiguous chunk [b*98, (b+1)*98)
  float pe = 0.f;
  {
    int i = b*98 + t;
    if (t < 98 && i < NBLK) pe = p_e[i];
  }
  pe += __shfl_xor(pe,1); pe += __shfl_xor(pe,2); pe += __shfl_xor(pe,4);
  pe += __shfl_xor(pe,8); pe += __shfl_xor(pe,16); pe += __shfl_xor(pe,32);
  if ((t&63)==0) red[t>>6] = pe;
  __syncthreads();
  if (t==0) ws[OFF_P2E + b] = red[0]+red[1]+red[2]+red[3];
}

// ---------------------------------------------------------------- reduce stage B + heads: 1 block
__global__ __launch_bounds__(256) void kredB(
    const float* __restrict__ val_W1, const float* __restrict__ val_b1,
    const float* __restrict__ val_W2, const float* __restrict__ val_b2,
    float* __restrict__ ws, float* __restrict__ d_out)
{
  __shared__ float aggL[64];
  __shared__ float red[256];
  __shared__ float Zs;
  const int t = threadIdx.x;
  // Z = sum of 64 stage-2 e-partials
  {
    float pe = (t < 64) ? ws[OFF_P2E + t] : 0.f;
    pe += __shfl_xor(pe,1); pe += __shfl_xor(pe,2); pe += __shfl_xor(pe,4);
    pe += __shfl_xor(pe,8); pe += __shfl_xor(pe,16); pe += __shfl_xor(pe,32);
    if (t==0){ Zs = pe; ws[OFF_MISC+1] = 1.f/pe; }
  }
  // agg[d] = sum over 256 stripes
  {
    int d = t&63, q = t>>6;
    float a = 0.f;
    #pragma unroll 4
    for (int s2=q; s2<256; s2+=4) a += ws[OFF_P2AGG + s2*64 + d];
    red[t] = a;
  }
  __syncthreads();
  if (t < 64) aggL[t] = (red[t] + red[64+t] + red[128+t] + red[192+t]) / Zs;
  __syncthreads();
  if (t < 32){
    float hv = val_b1[t];
    for (int k=0;k<64;++k) hv = fmaf(aggL[k], val_W1[t*64+k], hv);
    hv = fmaxf(hv, 0.f);
    float v = hv * val_W2[t];
    v += __shfl_xor(v,1); v += __shfl_xor(v,2); v += __shfl_xor(v,4);
    v += __shfl_xor(v,8); v += __shfl_xor(v,16);
    // q_value = value + (advantage - mean(advantage)) == value (advantage is [1])
    if (t==0) d_out[0] = (v + val_b2[0]) * ws[OFF_MISC+0];
  }
}

// ---------------------------------------------------------------- att weights out
__global__ __launch_bounds__(256) void kweights(
    const float* __restrict__ ws, float* __restrict__ d_out)
{
  int p = blockIdx.x*256 + threadIdx.x;
  if (p < P_TOT) d_out[1+p] = ws[OFF_E + p] * ws[OFF_MISC+1];
}

// ---------------------------------------------------------------- launch
extern "C" void kernel_launch(void* const* d_in, const int* in_sizes, int n_in,
                              void* d_out, int out_size, void* d_ws, size_t ws_size,
                              hipStream_t stream) {
  const int*   user_idx   = (const int*)  d_in[0];
  const int*   item_idx   = (const int*)  d_in[1];
  const int*   node_ids   = (const int*)  d_in[2];
  const int*   node_types = (const int*)  d_in[3];
  const int*   rel_idx    = (const int*)  d_in[4];
  const float* user_emb   = (const float*)d_in[5];
  const float* item_emb   = (const float*)d_in[6];
  const float* rel_emb    = (const float*)d_in[7];
  const float* ntype_emb  = (const float*)d_in[8];
  const float* W_ih       = (const float*)d_in[9];
  const float* W_hh       = (const float*)d_in[10];
  const float* b_ih       = (const float*)d_in[11];
  const float* b_hh       = (const float*)d_in[12];
  const float* att_W1     = (const float*)d_in[13];
  const float* att_b1     = (const float*)d_in[14];
  const float* att_W2     = (const float*)d_in[15];
  const float* att_b2     = (const float*)d_in[16];
  const float* val_W1     = (const float*)d_in[17];
  const float* val_b1     = (const float*)d_in[18];
  const float* val_W2     = (const float*)d_in[19];
  const float* val_b2     = (const float*)d_in[20];
  const float* saf_W1     = (const float*)d_in[25];
  const float* saf_b1     = (const float*)d_in[26];
  const float* saf_W2     = (const float*)d_in[27];
  const float* saf_b2     = (const float*)d_in[28];
  float* ws  = (float*)d_ws;
  float* out = (float*)d_out;

  hipLaunchKernelGGL(kprep, dim3(64), dim3(256), 0, stream,
                     user_idx, item_idx, user_emb, item_emb,
                     W_ih, W_hh, b_ih, b_hh, att_W1, att_b1,
                     saf_W1, saf_b1, saf_W2, saf_b2, ws);
  hipLaunchKernelGGL(klstm, dim3(NBLK), dim3(512), 0, stream,
                     node_ids, node_types, rel_idx,
                     user_emb, item_emb, rel_emb, ntype_emb,
                     att_W2, att_b2, ws);
  hipLaunchKernelGGL(kredA, dim3(64), dim3(256), 0, stream, ws);
  hipLaunchKernelGGL(kredB, dim3(1), dim3(256), 0, stream,
                     val_W1, val_b1, val_W2, val_b2, ws, out);
  hipLaunchKernelGGL(kweights, dim3((P_TOT+255)/256), dim3(256), 0, stream,
                     ws, out);
}

// Round 4
// 234.074 us; speedup vs baseline: 5.7562x; 1.0117x over previous
//
#include <hip/hip_runtime.h>
#include <math.h>

#define P_TOT 100000
#define BM    16
#define NBLK  6250

// ws float offsets
#define OFF_BIH   0        // 49152 f32-slots: 192 frag-blocks (6kc x 2hl x 16nt) x 1KB bf16
#define OFF_BHH   49152    // 16384: 64 frag-blocks (2kc x 2hl x 16nt)
#define OFF_BA    65536    // 8192:  32 frag-blocks (2kc x 2hl x 8nt)
#define OFF_BSUM  73728    // 256  (b_ih+b_hh, natural order)
#define OFF_CTXP  73984    // 128  (ctx part of att hidden preact)
#define OFF_MISC  74112    // [0]=safety, [1]=invZ
#define OFF_E     74128    // 100000 exp(score)
#define OFF_PE    174128   // 6250 partial sum e
#define OFF_PAGG  180384   // 6250*64 partial sum e*h
#define OFF_P2E   580384   // 64 stage-2 partial sum e
#define OFF_P2AGG 580448   // 256*64 stage-2 partial sum e*h
// bf16 hi/lo embedding tables: [row][128B hi | 128B lo] = 64 f32-slots/row
#define OFF_TAB   596864
#define OFF_TU    (OFF_TAB)                 // user:   100000 rows
#define OFF_TI    (OFF_TAB + 6400000)       // item:    50000 rows
#define OFF_TR    (OFF_TAB + 9600000)       // rel:         8 rows
#define OFF_TT    (OFF_TAB + 9600512)       // type:        2 rows
#define WS_FAST_BYTES ((size_t)(OFF_TAB + 9600640) * 4)

typedef short bf16x8 __attribute__((ext_vector_type(8)));
typedef float f32x4  __attribute__((ext_vector_type(4)));

#define MFMA16(a,b,c) __builtin_amdgcn_mfma_f32_16x16x32_bf16((a),(b),(c),0,0,0)

__device__ __forceinline__ void cvthl(float v, unsigned short& h, unsigned short& l){
  unsigned int u  = __float_as_uint(v);
  unsigned int hr = (u + 0x7fffu + ((u>>16)&1u)) >> 16;
  float hf = __uint_as_float(hr<<16);
  unsigned int u2 = __float_as_uint(v - hf);
  unsigned int lr = (u2 + 0x7fffu + ((u2>>16)&1u)) >> 16;
  h = (unsigned short)hr; l = (unsigned short)lr;
}
__device__ __forceinline__ float sigm_f(float x){ return 1.f/(1.f+__expf(-x)); }
__device__ __forceinline__ float tanh_f(float x){
  float e2 = __expf(2.f*x);
  return (e2-1.f)/(e2+1.f);
}

// ---------------------------------------------------------------- prep (weights)
__global__ __launch_bounds__(256) void kprep(
    const int* __restrict__ user_idx, const int* __restrict__ item_idx,
    const float* __restrict__ user_emb, const float* __restrict__ item_emb,
    const float* __restrict__ W_ih, const float* __restrict__ W_hh,
    const float* __restrict__ b_ih, const float* __restrict__ b_hh,
    const float* __restrict__ att_W1, const float* __restrict__ att_b1,
    const float* __restrict__ saf_W1, const float* __restrict__ saf_b1,
    const float* __restrict__ saf_W2, const float* __restrict__ saf_b2,
    float* __restrict__ ws)
{
  const int t = threadIdx.x;
  for (int fb = blockIdx.x; fb < 288; fb += gridDim.x){
    const float* src; int base, rowlen, kc, hl, ntg;
    if (fb < 192){ kc = fb>>5; int rem = fb&31; hl = rem>>4; ntg = rem&15;
                   base = OFF_BIH + fb*256; src = W_ih; rowlen = 192; }
    else if (fb < 256){ int f2 = fb-192; kc = f2>>5; int rem = f2&31; hl = rem>>4; ntg = rem&15;
                   base = OFF_BHH + f2*256; src = W_hh; rowlen = 64; }
    else { int f3 = fb-256; kc = f3>>4; int rem = f3&15; hl = rem>>3; ntg = rem&7;
                   base = OFF_BA + f3*256; src = att_W1; rowlen = 192; }
    unsigned short* dst = (unsigned short*)(ws + base);
    for (int e = t; e < 512; e += 256){
      int l = e>>3, j = e&7;
      int n = ntg*16 + (l&15);
      int k = kc*32 + (l>>4)*8 + j;
      float v = src[n*rowlen + k];
      unsigned short h, lo; cvthl(v, h, lo);
      dst[e] = hl ? lo : h;
    }
  }
  if (blockIdx.x == 0){
    __shared__ float ctx[128];
    if (t < 256) ws[OFF_BSUM+t] = b_ih[t] + b_hh[t];
    if (t < 64){
      ctx[t]    = user_emb[user_idx[0]*64 + t];
      ctx[64+t] = item_emb[item_idx[0]*64 + t];
    }
    __syncthreads();
    if (t < 128){
      float s = att_b1[t];
      for (int k=0;k<128;++k) s = fmaf(att_W1[t*192 + 64 + k], ctx[k], s);
      ws[OFF_CTXP + t] = s;
    }
    if (t < 32){
      float s = saf_b1[t];
      for (int k=0;k<128;++k) s = fmaf(saf_W1[t*128+k], ctx[k], s);
      s = fmaxf(s, 0.f);
      float v = s * saf_W2[t];
      v += __shfl_xor(v,1); v += __shfl_xor(v,2); v += __shfl_xor(v,4);
      v += __shfl_xor(v,8); v += __shfl_xor(v,16);
      if (t==0) ws[OFF_MISC+0] = 1.f/(1.f+expf(-(v + saf_b2[0])));
    }
  }
}

// ---------------------------------------------------------------- table conversion (fast path)
// rows: [0,100000) user | [100000,150000) item | [150000,150008) rel | [150008,150010) type
__global__ __launch_bounds__(256) void kconv(
    const float* __restrict__ user_emb, const float* __restrict__ item_emb,
    const float* __restrict__ relation_emb, const float* __restrict__ node_type_emb,
    float* __restrict__ ws)
{
  const int gid = blockIdx.x*256 + threadIdx.x;
  const int row = gid >> 3, seg = gid & 7;
  if (row >= 150010) return;
  const float* src; int dstoff;
  if (row < 100000){ src = user_emb + row*64;             dstoff = OFF_TU + row*64; }
  else if (row < 150000){ src = item_emb + (row-100000)*64; dstoff = OFF_TI + (row-100000)*64; }
  else if (row < 150008){ src = relation_emb + (row-150000)*64; dstoff = OFF_TR + (row-150000)*64; }
  else { src = node_type_emb + (row-150008)*64;           dstoff = OFF_TT + (row-150008)*64; }
  float4 v0 = ((const float4*)(src + seg*8))[0];
  float4 v1 = ((const float4*)(src + seg*8))[1];
  float vv[8] = {v0.x,v0.y,v0.z,v0.w,v1.x,v1.y,v1.z,v1.w};
  unsigned short h[8], lo[8];
  #pragma unroll
  for (int j=0;j<8;++j) cvthl(vv[j], h[j], lo[j]);
  uint4 hq, lq;
  hq.x = (unsigned)h[0] | ((unsigned)h[1]<<16);  hq.y = (unsigned)h[2] | ((unsigned)h[3]<<16);
  hq.z = (unsigned)h[4] | ((unsigned)h[5]<<16);  hq.w = (unsigned)h[6] | ((unsigned)h[7]<<16);
  lq.x = (unsigned)lo[0]| ((unsigned)lo[1]<<16); lq.y = (unsigned)lo[2]| ((unsigned)lo[3]<<16);
  lq.z = (unsigned)lo[4]| ((unsigned)lo[5]<<16); lq.w = (unsigned)lo[6]| ((unsigned)lo[7]<<16);
  char* dst = (char*)(ws + dstoff);
  *(uint4*)(dst + seg*16)       = hq;   // hi half: bytes [0,128)
  *(uint4*)(dst + 128 + seg*16) = lq;   // lo half: bytes [128,256)
}

// ---------------------------------------------------------------- main: LSTM + attention (MFMA split-bf16)
template<int PRE>
__global__ __launch_bounds__(512,4) void klstm(
    const int* __restrict__ node_ids, const int* __restrict__ node_types,
    const int* __restrict__ rel_idx,
    const float* __restrict__ user_emb, const float* __restrict__ item_emb,
    const float* __restrict__ relation_emb, const float* __restrict__ node_type_emb,
    const float* __restrict__ att_W2, const float* __restrict__ att_b2,
    float* __restrict__ ws)
{
  __shared__ __align__(16) unsigned char smem[49152];
  const int t   = threadIdx.x;
  const int l   = t & 63, wid = t >> 6;
  const int ln  = l & 15, lk = l >> 4;
  const int bid = blockIdx.x, p0 = bid*BM;
  const int n0  = wid*32;
  const bf16x8* Bih = (const bf16x8*)(ws + OFF_BIH);
  const bf16x8* Bhh = (const bf16x8*)(ws + OFF_BHH);
  const bf16x8* Bab = (const bf16x8*)(ws + OFF_BA);
  const int swA = (ln&7)<<4;

  // ---- gather feats (4 steps) -> swizzled bf16 hi/lo A tiles
  if (t < 384){
    int r = t>>1, half = t&1;
    int s = r/48, rem = r - s*48, src = rem>>4, p = rem&15;
    int gi = (p0+p)*4 + s;
    const int sw = (p&7)<<4;
    const int rowH = ((s*2+0)*16 + p)*384;
    const int rowL = ((s*2+1)*16 + p)*384;
    if (PRE){
      const char* rp;
      if (src==0){ int nid = node_ids[gi];
                   rp = (const char*)(ws + (node_types[gi]==0 ? OFF_TU + nid*64 : OFF_TI + nid*64)); }
      else if (src==1){ rp = (const char*)(ws + OFF_TT + node_types[gi]*64); }
      else { rp = (const char*)(ws + OFF_TR + rel_idx[gi]*64); }
      #pragma unroll
      for (int ii=0; ii<4; ++ii){
        int i = half*4 + ii;
        uint4 hq = *(const uint4*)(rp + i*16);
        uint4 lq = *(const uint4*)(rp + 128 + i*16);
        int kb = (src*64 + i*8)*2;
        *(uint4*)(smem + rowH + (kb ^ sw)) = hq;
        *(uint4*)(smem + rowL + (kb ^ sw)) = lq;
      }
    } else {
      const float* sp;
      if (src==0){ int nid = node_ids[gi]; sp = (node_types[gi]==0 ? user_emb : item_emb) + nid*64; }
      else if (src==1){ sp = node_type_emb + node_types[gi]*64; }
      else { sp = relation_emb + rel_idx[gi]*64; }
      #pragma unroll
      for (int ii=0; ii<4; ++ii){
        int i = half*4 + ii;
        float4 v0 = ((const float4*)sp)[i*2];
        float4 v1 = ((const float4*)sp)[i*2+1];
        float vv[8] = {v0.x,v0.y,v0.z,v0.w,v1.x,v1.y,v1.z,v1.w};
        unsigned short h[8], lo[8];
        #pragma unroll
        for (int j=0;j<8;++j) cvthl(vv[j], h[j], lo[j]);
        uint4 hq, lq;
        hq.x = (unsigned)h[0] | ((unsigned)h[1]<<16);  hq.y = (unsigned)h[2] | ((unsigned)h[3]<<16);
        hq.z = (unsigned)h[4] | ((unsigned)h[5]<<16);  hq.w = (unsigned)h[6] | ((unsigned)h[7]<<16);
        lq.x = (unsigned)lo[0]| ((unsigned)lo[1]<<16); lq.y = (unsigned)lo[2]| ((unsigned)lo[3]<<16);
        lq.z = (unsigned)lo[4]| ((unsigned)lo[5]<<16); lq.w = (unsigned)lo[6]| ((unsigned)lo[7]<<16);
        int kb = (src*64 + i*8)*2;
        *(uint4*)(smem + rowH + (kb ^ sw)) = hq;
        *(uint4*)(smem + rowL + (kb ^ sw)) = lq;
      }
    }
  }
  // ---- acc init with bias (Z = X@Wc^T + (b_ih+b_hh))
  f32x4 acc[4][2];
  #pragma unroll
  for (int s=0;s<4;++s)
    #pragma unroll
    for (int nt=0;nt<2;++nt){
      float bv = ws[OFF_BSUM + n0 + nt*16 + ln];
      acc[s][nt] = (f32x4){bv,bv,bv,bv};
    }
  __syncthreads();

  // ---- phase 1: Zfeat for all 4 steps (K=192), B frags reused across steps
  #pragma unroll 2
  for (int kc=0;kc<6;++kc){
    bf16x8 bh0 = Bih[(unsigned)(((kc*2+0)*16 + wid*2+0)*64 + l)];
    bf16x8 bh1 = Bih[(unsigned)(((kc*2+0)*16 + wid*2+1)*64 + l)];
    bf16x8 bl0 = Bih[(unsigned)(((kc*2+1)*16 + wid*2+0)*64 + l)];
    bf16x8 bl1 = Bih[(unsigned)(((kc*2+1)*16 + wid*2+1)*64 + l)];
    #pragma unroll
    for (int s=0;s<4;++s){
      bf16x8 ah = *(const bf16x8*)(smem + ((s*2+0)*16+ln)*384 + ((kc*64 + lk*16) ^ swA));
      bf16x8 al = *(const bf16x8*)(smem + ((s*2+1)*16+ln)*384 + ((kc*64 + lk*16) ^ swA));
      acc[s][0] = MFMA16(ah, bh0, acc[s][0]);
      acc[s][0] = MFMA16(al, bh0, acc[s][0]);
      acc[s][0] = MFMA16(ah, bl0, acc[s][0]);
      acc[s][1] = MFMA16(ah, bh1, acc[s][1]);
      acc[s][1] = MFMA16(al, bh1, acc[s][1]);
      acc[s][1] = MFMA16(ah, bl1, acc[s][1]);
    }
  }
  __syncthreads();   // Afeat dead; overlay region live from here

  // ---- phase 2: recurrence
  const int gp = t>>5, gd = (t&31)*2;     // gate thread -> (path, 2 dims)
  const int swg = (gp&7)<<4;
  float c0 = 0.f, c1 = 0.f;
  #pragma unroll
  for (int s=0;s<4;++s){
    if (s > 0){
      #pragma unroll
      for (int kc=0;kc<2;++kc){
        bf16x8 ah = *(const bf16x8*)(smem + 20480 +        ln*128 + ((kc*64 + lk*16) ^ swA));
        bf16x8 al = *(const bf16x8*)(smem + 20480 + 2048 + ln*128 + ((kc*64 + lk*16) ^ swA));
        bf16x8 bh0 = Bhh[(unsigned)(((kc*2+0)*16 + wid*2+0)*64 + l)];
        bf16x8 bh1 = Bhh[(unsigned)(((kc*2+0)*16 + wid*2+1)*64 + l)];
        bf16x8 bl0 = Bhh[(unsigned)(((kc*2+1)*16 + wid*2+0)*64 + l)];
        bf16x8 bl1 = Bhh[(unsigned)(((kc*2+1)*16 + wid*2+1)*64 + l)];
        acc[s][0] = MFMA16(ah, bh0, acc[s][0]);
        acc[s][0] = MFMA16(al, bh0, acc[s][0]);
        acc[s][0] = MFMA16(ah, bl0, acc[s][0]);
        acc[s][1] = MFMA16(ah, bh1, acc[s][1]);
        acc[s][1] = MFMA16(al, bh1, acc[s][1]);
        acc[s][1] = MFMA16(ah, bl1, acc[s][1]);
      }
    }
    // write Z tile to LDS (C layout: row=(l>>4)*4+r, col=l&15)
    #pragma unroll
    for (int nt=0;nt<2;++nt)
      #pragma unroll
      for (int r=0;r<4;++r)
        *(float*)(smem + (lk*4+r)*1024 + (n0 + nt*16 + ln)*4) = acc[s][nt][r];
    __syncthreads();
    // gates (f32): z = [i | f | g | o]
    {
      float2 zi = *(float2*)(smem + gp*1024 +        gd*4);
      float2 zf = *(float2*)(smem + gp*1024 + 256  + gd*4);
      float2 zg = *(float2*)(smem + gp*1024 + 512  + gd*4);
      float2 zo = *(float2*)(smem + gp*1024 + 768  + gd*4);
      float i0 = sigm_f(zi.x), i1 = sigm_f(zi.y);
      float f0 = sigm_f(zf.x), f1 = sigm_f(zf.y);
      float g0 = tanh_f(zg.x), g1 = tanh_f(zg.y);
      float o0 = sigm_f(zo.x), o1 = sigm_f(zo.y);
      c0 = fmaf(f0, c0, i0*g0);
      c1 = fmaf(f1, c1, i1*g1);
      float h0 = o0 * tanh_f(c0);
      float h1 = o1 * tanh_f(c1);
      if (s == 3) *(float2*)(smem + 16384 + gp*256 + gd*4) = make_float2(h0, h1);
      unsigned short hh0,ll0,hh1,ll1;
      cvthl(h0, hh0, ll0); cvthl(h1, hh1, ll1);
      *(unsigned*)(smem + 20480 +        gp*128 + ((gd*2) ^ swg)) = (unsigned)hh0 | ((unsigned)hh1<<16);
      *(unsigned*)(smem + 20480 + 2048 + gp*128 + ((gd*2) ^ swg)) = (unsigned)ll0 | ((unsigned)ll1<<16);
    }
    __syncthreads();
  }

  // ---- attention hidden: relu(h @ BA + ctxp)   (N=128 -> waves 0..3)
  if (wid < 4){
    f32x4 acc2[2];
    #pragma unroll
    for (int nt=0;nt<2;++nt){
      float cv = ws[OFF_CTXP + wid*32 + nt*16 + ln];
      acc2[nt] = (f32x4){cv,cv,cv,cv};
    }
    #pragma unroll
    for (int kc=0;kc<2;++kc){
      bf16x8 ah = *(const bf16x8*)(smem + 20480 +        ln*128 + ((kc*64 + lk*16) ^ swA));
      bf16x8 al = *(const bf16x8*)(smem + 20480 + 2048 + ln*128 + ((kc*64 + lk*16) ^ swA));
      bf16x8 bh0 = Bab[(unsigned)(((kc*2+0)*8 + wid*2+0)*64 + l)];
      bf16x8 bh1 = Bab[(unsigned)(((kc*2+0)*8 + wid*2+1)*64 + l)];
      bf16x8 bl0 = Bab[(unsigned)(((kc*2+1)*8 + wid*2+0)*64 + l)];
      bf16x8 bl1 = Bab[(unsigned)(((kc*2+1)*8 + wid*2+1)*64 + l)];
      acc2[0] = MFMA16(ah, bh0, acc2[0]);
      acc2[0] = MFMA16(al, bh0, acc2[0]);
      acc2[0] = MFMA16(ah, bl0, acc2[0]);
      acc2[1] = MFMA16(ah, bh1, acc2[1]);
      acc2[1] = MFMA16(al, bh1, acc2[1]);
      acc2[1] = MFMA16(ah, bl1, acc2[1]);
    }
    #pragma unroll
    for (int nt=0;nt<2;++nt)
      #pragma unroll
      for (int r=0;r<4;++r)
        *(float*)(smem + 24576 + (lk*4+r)*512 + (wid*32 + nt*16 + ln)*4) = fmaxf(acc2[nt][r], 0.f);
  }
  __syncthreads();
  // ---- score = hidden . att_W2 + b2 ; e = exp(score)
  {
    int sp2 = t>>5, seg = t&31;
    float4 a = *(const float4*)(smem + 24576 + sp2*512 + seg*16);
    float4 w = *(const float4*)(att_W2 + seg*4);
    float sc = a.x*w.x; sc = fmaf(a.y,w.y,sc); sc = fmaf(a.z,w.z,sc); sc = fmaf(a.w,w.w,sc);
    sc += __shfl_xor(sc,1); sc += __shfl_xor(sc,2); sc += __shfl_xor(sc,4);
    sc += __shfl_xor(sc,8); sc += __shfl_xor(sc,16);
    if (seg == 0){
      float e = __expf(sc + att_b2[0]);
      *(float*)(smem + 32768 + sp2*4) = e;
      ws[OFF_E + p0 + sp2] = e;
    }
  }
  __syncthreads();
  // ---- partial sums: sum(e), sum(e*h)
  {
    int pg = t>>6, d = t&63;
    const float* es = (const float*)(smem + 32768);
    float a = es[pg*2]   * (*(const float*)(smem + 16384 + (pg*2  )*256 + d*4))
            + es[pg*2+1] * (*(const float*)(smem + 16384 + (pg*2+1)*256 + d*4));
    *(float*)(smem + 32896 + (pg*64+d)*4) = a;
  }
  __syncthreads();
  if (t < 64){
    const float* part = (const float*)(smem + 32896);
    float a = 0.f;
    #pragma unroll
    for (int pg=0;pg<8;++pg) a += part[pg*64 + t];
    ws[OFF_PAGG + bid*64 + t] = a;
  }
  if (t < 16){
    float e2 = *(const float*)(smem + 32768 + t*4);
    e2 += __shfl_xor(e2,1); e2 += __shfl_xor(e2,2);
    e2 += __shfl_xor(e2,4); e2 += __shfl_xor(e2,8);
    if (t==0) ws[OFF_PE + bid] = e2;
  }
}

// ---------------------------------------------------------------- reduce stage A: 64 blocks
__global__ __launch_bounds__(256) void kredA(float* __restrict__ ws)
{
  const float* p_e   = ws + OFF_PE;
  const float* p_agg = ws + OFF_PAGG;
  __shared__ float red[256];
  const int b = blockIdx.x, t = threadIdx.x;
  const int s = b*4 + (t>>6), d = t&63;
  float a = 0.f;
  for (int row = s; row < NBLK; row += 256) a += p_agg[row*64 + d];
  ws[OFF_P2AGG + s*64 + d] = a;
  float pe = 0.f;
  {
    int i = b*98 + t;
    if (t < 98 && i < NBLK) pe = p_e[i];
  }
  pe += __shfl_xor(pe,1); pe += __shfl_xor(pe,2); pe += __shfl_xor(pe,4);
  pe += __shfl_xor(pe,8); pe += __shfl_xor(pe,16); pe += __shfl_xor(pe,32);
  if ((t&63)==0) red[t>>6] = pe;
  __syncthreads();
  if (t==0) ws[OFF_P2E + b] = red[0]+red[1]+red[2]+red[3];
}

// ---------------------------------------------------------------- reduce stage B + heads: 1 block
__global__ __launch_bounds__(256) void kredB(
    const float* __restrict__ val_W1, const float* __restrict__ val_b1,
    const float* __restrict__ val_W2, const float* __restrict__ val_b2,
    float* __restrict__ ws, float* __restrict__ d_out)
{
  __shared__ float aggL[64];
  __shared__ float red[256];
  __shared__ float Zs;
  const int t = threadIdx.x;
  {
    float pe = (t < 64) ? ws[OFF_P2E + t] : 0.f;
    pe += __shfl_xor(pe,1); pe += __shfl_xor(pe,2); pe += __shfl_xor(pe,4);
    pe += __shfl_xor(pe,8); pe += __shfl_xor(pe,16); pe += __shfl_xor(pe,32);
    if (t==0){ Zs = pe; ws[OFF_MISC+1] = 1.f/pe; }
  }
  {
    int d = t&63, q = t>>6;
    float a = 0.f;
    #pragma unroll 4
    for (int s2=q; s2<256; s2+=4) a += ws[OFF_P2AGG + s2*64 + d];
    red[t] = a;
  }
  __syncthreads();
  if (t < 64) aggL[t] = (red[t] + red[64+t] + red[128+t] + red[192+t]) / Zs;
  __syncthreads();
  if (t < 32){
    float hv = val_b1[t];
    for (int k=0;k<64;++k) hv = fmaf(aggL[k], val_W1[t*64+k], hv);
    hv = fmaxf(hv, 0.f);
    float v = hv * val_W2[t];
    v += __shfl_xor(v,1); v += __shfl_xor(v,2); v += __shfl_xor(v,4);
    v += __shfl_xor(v,8); v += __shfl_xor(v,16);
    // q_value = value + (advantage - mean(advantage)) == value (advantage is [1])
    if (t==0) d_out[0] = (v + val_b2[0]) * ws[OFF_MISC+0];
  }
}

// ---------------------------------------------------------------- att weights out
__global__ __launch_bounds__(256) void kweights(
    const float* __restrict__ ws, float* __restrict__ d_out)
{
  int p = blockIdx.x*256 + threadIdx.x;
  if (p < P_TOT) d_out[1+p] = ws[OFF_E + p] * ws[OFF_MISC+1];
}

// ---------------------------------------------------------------- launch
extern "C" void kernel_launch(void* const* d_in, const int* in_sizes, int n_in,
                              void* d_out, int out_size, void* d_ws, size_t ws_size,
                              hipStream_t stream) {
  const int*   user_idx   = (const int*)  d_in[0];
  const int*   item_idx   = (const int*)  d_in[1];
  const int*   node_ids   = (const int*)  d_in[2];
  const int*   node_types = (const int*)  d_in[3];
  const int*   rel_idx    = (const int*)  d_in[4];
  const float* user_emb   = (const float*)d_in[5];
  const float* item_emb   = (const float*)d_in[6];
  const float* rel_emb    = (const float*)d_in[7];
  const float* ntype_emb  = (const float*)d_in[8];
  const float* W_ih       = (const float*)d_in[9];
  const float* W_hh       = (const float*)d_in[10];
  const float* b_ih       = (const float*)d_in[11];
  const float* b_hh       = (const float*)d_in[12];
  const float* att_W1     = (const float*)d_in[13];
  const float* att_b1     = (const float*)d_in[14];
  const float* att_W2     = (const float*)d_in[15];
  const float* att_b2     = (const float*)d_in[16];
  const float* val_W1     = (const float*)d_in[17];
  const float* val_b1     = (const float*)d_in[18];
  const float* val_W2     = (const float*)d_in[19];
  const float* val_b2     = (const float*)d_in[20];
  const float* saf_W1     = (const float*)d_in[25];
  const float* saf_b1     = (const float*)d_in[26];
  const float* saf_W2     = (const float*)d_in[27];
  const float* saf_b2     = (const float*)d_in[28];
  float* ws  = (float*)d_ws;
  float* out = (float*)d_out;

  const bool fast = (ws_size >= WS_FAST_BYTES);

  hipLaunchKernelGGL(kprep, dim3(64), dim3(256), 0, stream,
                     user_idx, item_idx, user_emb, item_emb,
                     W_ih, W_hh, b_ih, b_hh, att_W1, att_b1,
                     saf_W1, saf_b1, saf_W2, saf_b2, ws);
  if (fast){
    hipLaunchKernelGGL(kconv, dim3((150010*8+255)/256), dim3(256), 0, stream,
                       user_emb, item_emb, rel_emb, ntype_emb, ws);
    hipLaunchKernelGGL(klstm<1>, dim3(NBLK), dim3(512), 0, stream,
                       node_ids, node_types, rel_idx,
                       user_emb, item_emb, rel_emb, ntype_emb,
                       att_W2, att_b2, ws);
  } else {
    hipLaunchKernelGGL(klstm<0>, dim3(NBLK), dim3(512), 0, stream,
                       node_ids, node_types, rel_idx,
                       user_emb, item_emb, rel_emb, ntype_emb,
                       att_W2, att_b2, ws);
  }
  hipLaunchKernelGGL(kredA, dim3(64), dim3(256), 0, stream, ws);
  hipLaunchKernelGGL(kredB, dim3(1), dim3(256), 0, stream,
                     val_W1, val_b1, val_W2, val_b2, ws, out);
  hipLaunchKernelGGL(kweights, dim3((P_TOT+255)/256), dim3(256), 0, stream,
                     ws, out);
}